// Round 1
// baseline (222.813 us; speedup 1.0000x reference)
//
#include <hip/hip_runtime.h>
#include <stdint.h>

// Problem constants: L=512, B=4, E=512, H=8, D=64
// Pipeline:
//  K0 conv   : fp32 -> bf16 (hi/lo split for in_proj operands)
//  K1 inproj : qkv = query @ W^T + b  (split-bf16 MFMA, ~fp32 accuracy)
//              -> q_s fp32 (scaled), q_bf, k_bf, v_bf  in (B,H,L,D)
//  K1b vtrans: v_bf (B,H,L,D) -> v_t (B,H,D,L)   (PV B-operand contiguity)
//  K2 scores : content scores = q.k^T per (b,h)   (bf16 MFMA) -> scores fp32
//  K3 rk+sm  : scores += sum_d q*rk_flat(d,j); softmax; -> w_bf (bf16 probs)
//  K5 pv     : attn = w @ v per (b,h)             (bf16 MFMA) -> attn fp32
//  K4 rv+fin : attn += sum_j w*rv; -> attn_bf in (L,B,E) layout
//  K6 outproj: out = attn @ Wo^T + b              (bf16 MFMA) -> d_out fp32

typedef short short8 __attribute__((ext_vector_type(8)));
typedef float f32x4 __attribute__((ext_vector_type(4)));

static __device__ __forceinline__ uint16_t f2bf(float f) {
  uint32_t u = __float_as_uint(f);
  uint32_t r = (u + 0x7FFFu + ((u >> 16) & 1u)) >> 16;
  return (uint16_t)r;
}
static __device__ __forceinline__ float bf2f(uint16_t h) {
  return __uint_as_float(((uint32_t)h) << 16);
}
static __device__ __forceinline__ short8 ld8(const uint16_t* p) {
  return *(const short8*)p;
}
#define MFMA(a, b, c) __builtin_amdgcn_mfma_f32_16x16x32_bf16((a), (b), (c), 0, 0, 0)

// ---------------- K0: fp32 -> bf16 (optionally hi/lo split) ----------------
__global__ void k_conv(const float* __restrict__ in, uint16_t* __restrict__ hi,
                       uint16_t* __restrict__ lo, int n) {
  int i = blockIdx.x * blockDim.x + threadIdx.x;
  int stride = gridDim.x * blockDim.x;
  for (; i < n; i += stride) {
    float f = in[i];
    uint16_t h = f2bf(f);
    hi[i] = h;
    if (lo) lo[i] = f2bf(f - bf2f(h));
  }
}

// ---------------- K1: in_proj split-bf16 MFMA GEMM ----------------
// C(2048 x 1536) = A(2048 x 512) * W^T ; A rows r = l*4+b
__global__ __launch_bounds__(256) void k_inproj(
    const uint16_t* __restrict__ a_hi, const uint16_t* __restrict__ a_lo,
    const uint16_t* __restrict__ w_hi, const uint16_t* __restrict__ w_lo,
    const float* __restrict__ bias, float* __restrict__ q_s,
    uint16_t* __restrict__ q_bf, uint16_t* __restrict__ k_bf,
    uint16_t* __restrict__ v_bf) {
  const int wave = threadIdx.x >> 6, lane = threadIdx.x & 63;
  const int wr = wave >> 1, wc = wave & 1;
  const int rif = lane & 15, kg = lane >> 4;
  const int rbase = blockIdx.x * 64 + wr * 32;
  const int cbase = blockIdx.y * 64 + wc * 32;
  f32x4 acc[2][2] = {};
  for (int ks = 0; ks < 512; ks += 32) {
    int kofs = ks + kg * 8;
    short8 aH[2], aL[2], bH[2], bL[2];
#pragma unroll
    for (int m = 0; m < 2; ++m) {
      size_t idx = (size_t)(rbase + m * 16 + rif) * 512 + kofs;
      aH[m] = ld8(a_hi + idx);
      aL[m] = ld8(a_lo + idx);
    }
#pragma unroll
    for (int n = 0; n < 2; ++n) {
      size_t idx = (size_t)(cbase + n * 16 + rif) * 512 + kofs;
      bH[n] = ld8(w_hi + idx);
      bL[n] = ld8(w_lo + idx);
    }
#pragma unroll
    for (int m = 0; m < 2; ++m)
#pragma unroll
      for (int n = 0; n < 2; ++n) {
        acc[m][n] = MFMA(aH[m], bH[n], acc[m][n]);
        acc[m][n] = MFMA(aH[m], bL[n], acc[m][n]);
        acc[m][n] = MFMA(aL[m], bH[n], acc[m][n]);
      }
  }
#pragma unroll
  for (int m = 0; m < 2; ++m)
#pragma unroll
    for (int n = 0; n < 2; ++n)
#pragma unroll
      for (int r = 0; r < 4; ++r) {
        int row = rbase + m * 16 + kg * 4 + r;  // C/D: row=(lane>>4)*4+reg
        int col = cbase + n * 16 + rif;         // C/D: col=lane&15
        float val = acc[m][n][r] + bias[col];
        int l = row >> 2, b = row & 3;
        int sel = col >> 9, h = (col >> 6) & 7, d = col & 63;
        size_t oidx = ((size_t)(b * 8 + h) * 512 + l) * 64 + d;
        if (sel == 0) {
          val *= 0.125f;  // 1/sqrt(64)
          q_s[oidx] = val;
          q_bf[oidx] = f2bf(val);
        } else if (sel == 1) {
          k_bf[oidx] = f2bf(val);
        } else {
          v_bf[oidx] = f2bf(val);
        }
      }
}

// ---------------- K1b: per-(b,h) transpose v (L,D)->(D,L) ----------------
__global__ __launch_bounds__(256) void k_vtrans(const uint16_t* __restrict__ v_bf,
                                                uint16_t* __restrict__ v_t) {
  __shared__ uint16_t tile[512 * 64];  // 64 KiB
  const size_t base = (size_t)blockIdx.x * 512 * 64;
  const uint4* s4 = (const uint4*)(v_bf + base);
  uint4* t4 = (uint4*)tile;
#pragma unroll
  for (int it = 0; it < 16; ++it) t4[it * 256 + threadIdx.x] = s4[it * 256 + threadIdx.x];
  __syncthreads();
  uint16_t* dst = v_t + base;
  int d = threadIdx.x >> 2, jb = (threadIdx.x & 3) * 128;
  for (int c = 0; c < 16; ++c) {
    int j0 = jb + c * 8;
    uint16_t tmp[8];
#pragma unroll
    for (int e = 0; e < 8; ++e) tmp[e] = tile[(j0 + e) * 64 + d];
    *(uint4*)(dst + (size_t)d * 512 + j0) = *(uint4*)tmp;
  }
}

// ---------------- K2: content scores per (b,h) ----------------
__global__ __launch_bounds__(256) void k_scores(const uint16_t* __restrict__ q_bf,
                                                const uint16_t* __restrict__ k_bf,
                                                float* __restrict__ scores) {
  const int bh = blockIdx.x;
  const uint16_t* qb = q_bf + (size_t)bh * 512 * 64;
  const uint16_t* kb = k_bf + (size_t)bh * 512 * 64;
  const int wave = threadIdx.x >> 6, lane = threadIdx.x & 63;
  const int wr = wave >> 1, wc = wave & 1;
  const int rif = lane & 15, kg = lane >> 4;
  const int ibase = blockIdx.y * 64 + wr * 32;
  const int jbase = blockIdx.z * 64 + wc * 32;
  f32x4 acc[2][2] = {};
#pragma unroll
  for (int ks = 0; ks < 64; ks += 32) {
    int kofs = ks + kg * 8;
    short8 A[2], Bb[2];
#pragma unroll
    for (int m = 0; m < 2; ++m) A[m] = ld8(qb + (size_t)(ibase + m * 16 + rif) * 64 + kofs);
#pragma unroll
    for (int n = 0; n < 2; ++n) Bb[n] = ld8(kb + (size_t)(jbase + n * 16 + rif) * 64 + kofs);
#pragma unroll
    for (int m = 0; m < 2; ++m)
#pragma unroll
      for (int n = 0; n < 2; ++n) acc[m][n] = MFMA(A[m], Bb[n], acc[m][n]);
  }
  float* sc = scores + (size_t)bh * 512 * 512;
#pragma unroll
  for (int m = 0; m < 2; ++m)
#pragma unroll
    for (int n = 0; n < 2; ++n)
#pragma unroll
      for (int r = 0; r < 4; ++r)
        sc[(size_t)(ibase + m * 16 + kg * 4 + r) * 512 + (jbase + n * 16 + rif)] = acc[m][n][r];
}

// ---------------- K3: rk einsum (fp32, streaming) + softmax ----------------
// one workgroup per (b,i); streams rk block (512*64 fp32 = 128KB)
__global__ __launch_bounds__(256) void k_rksoftmax(
    const float* __restrict__ relation_k, const float* __restrict__ q_s,
    const float* __restrict__ scores, uint16_t* __restrict__ w_bf) {
  __shared__ float qv[64 * 8];   // [d][h]
  __shared__ float sx[8 * 512];  // [h][j]
  const int b = blockIdx.x >> 9, i = blockIdx.x & 511;
  const int t = threadIdx.x;
  for (int e = t; e < 512; e += 256) {
    int h = e >> 6, d = e & 63;
    qv[d * 8 + h] = q_s[(((size_t)b * 8 + h) * 512 + i) * 64 + d];
  }
  __syncthreads();
  const int quad = t & 127, rep = t >> 7;
  const int j0 = quad * 4;
  const float* rkb = relation_k + ((size_t)b * 512 + i) * 32768;  // (D,L) flat view
  f32x4 acc[8] = {};
  for (int dd = 0; dd < 32; ++dd) {
    int d = rep * 32 + dd;
    f32x4 rk4 = *(const f32x4*)(rkb + (size_t)d * 512 + j0);
    f32x4 q0 = *(const f32x4*)&qv[d * 8];
    f32x4 q1 = *(const f32x4*)&qv[d * 8 + 4];
#pragma unroll
    for (int h = 0; h < 4; ++h)
#pragma unroll
      for (int c = 0; c < 4; ++c) acc[h][c] += q0[h] * rk4[c];
#pragma unroll
    for (int h = 0; h < 4; ++h)
#pragma unroll
      for (int c = 0; c < 4; ++c) acc[4 + h][c] += q1[h] * rk4[c];
  }
  if (rep == 1) {
#pragma unroll
    for (int h = 0; h < 8; ++h) *(f32x4*)&sx[h * 512 + j0] = acc[h];
  }
  __syncthreads();
  if (rep == 0) {
#pragma unroll
    for (int h = 0; h < 8; ++h) {
      f32x4 o = *(f32x4*)&sx[h * 512 + j0];
#pragma unroll
      for (int c = 0; c < 4; ++c) o[c] += acc[h][c];
      *(f32x4*)&sx[h * 512 + j0] = o;
    }
  }
  __syncthreads();
  // softmax: wave -> 2 heads, lane-parallel over j
  const int wave = t >> 6, lane = t & 63;
  for (int hh = 0; hh < 2; ++hh) {
    int h = wave * 2 + hh;
    const float* srow = scores + (((size_t)b * 8 + h) * 512 + i) * 512;
    float s[8], m = -1e30f;
#pragma unroll
    for (int jj = 0; jj < 8; ++jj) {
      int j = jj * 64 + lane;
      s[jj] = srow[j] + sx[h * 512 + j];
      m = fmaxf(m, s[jj]);
    }
    for (int o = 32; o > 0; o >>= 1) m = fmaxf(m, __shfl_xor(m, o));
    float e[8], sum = 0.f;
#pragma unroll
    for (int jj = 0; jj < 8; ++jj) {
      e[jj] = __expf(s[jj] - m);
      sum += e[jj];
    }
    for (int o = 32; o > 0; o >>= 1) sum += __shfl_xor(sum, o);
    float r = 1.f / sum;
    uint16_t* wrow = w_bf + (((size_t)b * 8 + h) * 512 + i) * 512;
#pragma unroll
    for (int jj = 0; jj < 8; ++jj) wrow[jj * 64 + lane] = f2bf(e[jj] * r);
  }
}

// ---------------- K5: PV MFMA per (b,h): attn = w(512x512) @ v(512x64) ----------------
__global__ __launch_bounds__(256) void k_pv(const uint16_t* __restrict__ w_bf,
                                            const uint16_t* __restrict__ v_t,
                                            float* __restrict__ attn) {
  const int bh = blockIdx.x;
  const uint16_t* wb = w_bf + (size_t)bh * 512 * 512;
  const uint16_t* vt = v_t + (size_t)bh * 64 * 512;
  const int wave = threadIdx.x >> 6, lane = threadIdx.x & 63;
  const int wr = wave >> 1, wc = wave & 1;
  const int rif = lane & 15, kg = lane >> 4;
  const int ibase = blockIdx.y * 64 + wr * 32;
  const int dbase = wc * 32;
  f32x4 acc[2][2] = {};
  for (int ks = 0; ks < 512; ks += 32) {
    int kofs = ks + kg * 8;
    short8 A[2], Bb[2];
#pragma unroll
    for (int m = 0; m < 2; ++m) A[m] = ld8(wb + (size_t)(ibase + m * 16 + rif) * 512 + kofs);
#pragma unroll
    for (int n = 0; n < 2; ++n) Bb[n] = ld8(vt + (size_t)(dbase + n * 16 + rif) * 512 + kofs);
#pragma unroll
    for (int m = 0; m < 2; ++m)
#pragma unroll
      for (int n = 0; n < 2; ++n) acc[m][n] = MFMA(A[m], Bb[n], acc[m][n]);
  }
#pragma unroll
  for (int m = 0; m < 2; ++m)
#pragma unroll
    for (int n = 0; n < 2; ++n)
#pragma unroll
      for (int r = 0; r < 4; ++r)
        attn[((size_t)bh * 512 + ibase + m * 16 + kg * 4 + r) * 64 + (dbase + n * 16 + rif)] =
            acc[m][n][r];
}

// ---------------- K4: rv einsum (fp32, streaming) + finalize ----------------
// one workgroup per (b,i); streams rv block (512*64 fp32 = 128KB)
__global__ __launch_bounds__(256) void k_rv(const float* __restrict__ relation_v,
                                            const uint16_t* __restrict__ w_bf,
                                            const float* __restrict__ attn,
                                            uint16_t* __restrict__ attn_bf) {
  __shared__ float wT[512 * 8];          // [j][h]
  __shared__ float partials[4 * 8 * 64]; // [wave][h][d]
  const int b = blockIdx.x >> 9, i = blockIdx.x & 511;
  const int t = threadIdx.x;
  {
    int h = t >> 5, jb = (t & 31) * 16;
    const uint16_t* wrow = w_bf + (((size_t)b * 8 + h) * 512 + i) * 512 + jb;
    uint16_t tmp[16];
    *(uint4*)tmp = *(const uint4*)wrow;
    *(uint4*)(tmp + 8) = *(const uint4*)(wrow + 8);
#pragma unroll
    for (int m = 0; m < 16; ++m) wT[(jb + m) * 8 + h] = bf2f(tmp[m]);
  }
  __syncthreads();
  const int wave = t >> 6, lane = t & 63;
  const float* rvb = relation_v + ((size_t)b * 512 + i) * 32768;
  float acc[8] = {};
  for (int jj = 0; jj < 128; ++jj) {
    int j = wave * 128 + jj;
    float rv = rvb[(size_t)j * 64 + lane];
    f32x4 w0 = *(const f32x4*)&wT[j * 8];
    f32x4 w1 = *(const f32x4*)&wT[j * 8 + 4];
#pragma unroll
    for (int h = 0; h < 4; ++h) acc[h] += w0[h] * rv;
#pragma unroll
    for (int h = 0; h < 4; ++h) acc[4 + h] += w1[h] * rv;
  }
#pragma unroll
  for (int h = 0; h < 8; ++h) partials[(wave * 8 + h) * 64 + lane] = acc[h];
  __syncthreads();
  for (int e = t; e < 512; e += 256) {
    int h = e >> 6, d = e & 63;
    float s = attn[(((size_t)b * 8 + h) * 512 + i) * 64 + d];
#pragma unroll
    for (int ww = 0; ww < 4; ++ww) s += partials[(ww * 8 + h) * 64 + d];
    attn_bf[((size_t)i * 4 + b) * 512 + h * 64 + d] = f2bf(s);  // (L,B,E)
  }
}

// ---------------- K6: out_proj bf16 MFMA ----------------
__global__ __launch_bounds__(256) void k_outproj(const uint16_t* __restrict__ attn_bf,
                                                 const uint16_t* __restrict__ wo_bf,
                                                 const float* __restrict__ bias,
                                                 float* __restrict__ out) {
  const int wave = threadIdx.x >> 6, lane = threadIdx.x & 63;
  const int wr = wave >> 1, wc = wave & 1;
  const int rif = lane & 15, kg = lane >> 4;
  const int rbase = blockIdx.x * 64 + wr * 32;
  const int cbase = blockIdx.y * 64 + wc * 32;
  f32x4 acc[2][2] = {};
  for (int ks = 0; ks < 512; ks += 32) {
    int kofs = ks + kg * 8;
    short8 A[2], Bb[2];
#pragma unroll
    for (int m = 0; m < 2; ++m) A[m] = ld8(attn_bf + (size_t)(rbase + m * 16 + rif) * 512 + kofs);
#pragma unroll
    for (int n = 0; n < 2; ++n) Bb[n] = ld8(wo_bf + (size_t)(cbase + n * 16 + rif) * 512 + kofs);
#pragma unroll
    for (int m = 0; m < 2; ++m)
#pragma unroll
      for (int n = 0; n < 2; ++n) acc[m][n] = MFMA(A[m], Bb[n], acc[m][n]);
  }
#pragma unroll
  for (int m = 0; m < 2; ++m)
#pragma unroll
    for (int n = 0; n < 2; ++n)
#pragma unroll
      for (int r = 0; r < 4; ++r) {
        int row = rbase + m * 16 + kg * 4 + r;
        int col = cbase + n * 16 + rif;
        out[(size_t)row * 512 + col] = acc[m][n][r] + bias[col];
      }
}

extern "C" void kernel_launch(void* const* d_in, const int* in_sizes, int n_in,
                              void* d_out, int out_size, void* d_ws, size_t ws_size,
                              hipStream_t stream) {
  const float* query = (const float*)d_in[0];
  const float* relation_k = (const float*)d_in[1];
  const float* relation_v = (const float*)d_in[2];
  const float* in_w = (const float*)d_in[3];
  const float* in_b = (const float*)d_in[4];
  const float* out_w = (const float*)d_in[5];
  const float* out_b = (const float*)d_in[6];
  float* out = (float*)d_out;
  char* ws = (char*)d_ws;

  uint16_t* a_hi  = (uint16_t*)(ws + 0);          // 2 MB   query hi
  uint16_t* a_lo  = (uint16_t*)(ws + 2097152);    // 2 MB   query lo
  uint16_t* w_hi  = (uint16_t*)(ws + 4194304);    // 1.5 MB in_proj_w hi
  uint16_t* w_lo  = (uint16_t*)(ws + 5767168);    // 1.5 MB in_proj_w lo
  uint16_t* wo_bf = (uint16_t*)(ws + 7340032);    // 0.5 MB out_proj_w
  float*    q_s   = (float*)   (ws + 7864320);    // 4 MB   q scaled fp32 (B,H,L,D)
  uint16_t* q_bf  = (uint16_t*)(ws + 12058624);   // 2 MB
  uint16_t* k_bf  = (uint16_t*)(ws + 14155776);   // 2 MB
  uint16_t* v_bf  = (uint16_t*)(ws + 16252928);   // 2 MB
  uint16_t* v_t   = (uint16_t*)(ws + 18350080);   // 2 MB   (B,H,D,L)
  float*    attn  = (float*)   (ws + 20447232);   // 4 MB   (B,H,L,D)
  uint16_t* attn_bf = (uint16_t*)(ws + 24641536); // 2 MB   (L,B,E)
  uint16_t* wprob = (uint16_t*)(ws + 26738688);   // 16 MB  softmax probs bf16 (B,H,L,L)
  float*    scores = (float*)  (ws + 43515904);   // 32 MB  content scores fp32
  // total 77,070,336 bytes

  k_conv<<<dim3(768), 256, 0, stream>>>(in_w, w_hi, w_lo, 1536 * 512);
  k_conv<<<dim3(1024), 256, 0, stream>>>(query, a_hi, a_lo, 2048 * 512);
  k_conv<<<dim3(256), 256, 0, stream>>>(out_w, wo_bf, (uint16_t*)nullptr, 512 * 512);
  k_inproj<<<dim3(32, 24), 256, 0, stream>>>(a_hi, a_lo, w_hi, w_lo, in_b, q_s, q_bf, k_bf, v_bf);
  k_vtrans<<<dim3(32), 256, 0, stream>>>(v_bf, v_t);
  k_scores<<<dim3(32, 8, 8), 256, 0, stream>>>(q_bf, k_bf, scores);
  k_rksoftmax<<<dim3(2048), 256, 0, stream>>>(relation_k, q_s, scores, wprob);
  k_pv<<<dim3(32, 8), 256, 0, stream>>>(wprob, v_t, attn);
  k_rv<<<dim3(2048), 256, 0, stream>>>(relation_v, wprob, attn, attn_bf);
  k_outproj<<<dim3(32, 8), 256, 0, stream>>>(attn_bf, wo_bf, out_b, out);
}

// Round 2
// 204.665 us; speedup vs baseline: 1.0887x; 1.0887x over previous
//
#include <hip/hip_runtime.h>
#include <hip/hip_fp16.h>
#include <stdint.h>

// L=512, B=4, E=512, H=8, D=64
// Pipeline (6 launches):
//  K0 conv_all : fp32 -> bf16 (hi/lo split) for in_w, query; hi for out_w
//  K1 inproj   : qkv = query @ W^T + b (split-bf16 MFMA) -> q_s fp32, q/k/v bf16 (B,H,L,D)
//  K2 scores   : content scores = q.k^T per (b,h) (bf16 MFMA) -> scores fp16
//  K3 mega     : per (b,i): rk-einsum fp32 + softmax -> w (LDS + global wprob)
//                + rv-einsum via MFMA -> rv_bf (L,B,E bf16)
//  K4 pv       : attn_pv = w @ v per (b,h) (bf16 MFMA, strided v loads) -> pv_bf (L,B,E)
//  K5 outproj  : out = (rv_bf+pv_bf) @ Wo^T + b (bf16 MFMA) -> d_out fp32

typedef short short8 __attribute__((ext_vector_type(8)));
typedef float f32x4 __attribute__((ext_vector_type(4)));
typedef unsigned short u16x4 __attribute__((ext_vector_type(4)));

static __device__ __forceinline__ uint16_t f2bf(float f) {
  uint32_t u = __float_as_uint(f);
  uint32_t r = (u + 0x7FFFu + ((u >> 16) & 1u)) >> 16;
  return (uint16_t)r;
}
static __device__ __forceinline__ float bf2f(uint16_t h) {
  return __uint_as_float(((uint32_t)h) << 16);
}
static __device__ __forceinline__ short8 ld8(const uint16_t* p) {
  return *(const short8*)p;
}
#define MFMA(a, b, c) __builtin_amdgcn_mfma_f32_16x16x32_bf16((a), (b), (c), 0, 0, 0)

// ---------------- K0: merged fp32 -> bf16 conversions ----------------
// region 0: in_w   786432 elems -> w_hi/w_lo
// region 1: query 1048576 elems -> a_hi/a_lo
// region 2: out_w  262144 elems -> wo_bf
__global__ __launch_bounds__(256) void k_conv_all(
    const float* __restrict__ in_w, const float* __restrict__ query,
    const float* __restrict__ out_w, uint16_t* __restrict__ w_hi,
    uint16_t* __restrict__ w_lo, uint16_t* __restrict__ a_hi,
    uint16_t* __restrict__ a_lo, uint16_t* __restrict__ wo_bf) {
  int e = (blockIdx.x * 256 + threadIdx.x) * 4;
  if (e < 786432) {
    f32x4 v = *(const f32x4*)(in_w + e);
    u16x4 hi, lo;
#pragma unroll
    for (int k = 0; k < 4; ++k) {
      hi[k] = f2bf(v[k]);
      lo[k] = f2bf(v[k] - bf2f(hi[k]));
    }
    *(u16x4*)(w_hi + e) = hi;
    *(u16x4*)(w_lo + e) = lo;
  } else if (e < 786432 + 1048576) {
    int o = e - 786432;
    f32x4 v = *(const f32x4*)(query + o);
    u16x4 hi, lo;
#pragma unroll
    for (int k = 0; k < 4; ++k) {
      hi[k] = f2bf(v[k]);
      lo[k] = f2bf(v[k] - bf2f(hi[k]));
    }
    *(u16x4*)(a_hi + o) = hi;
    *(u16x4*)(a_lo + o) = lo;
  } else {
    int o = e - 1835008;
    f32x4 v = *(const f32x4*)(out_w + o);
    u16x4 hi;
#pragma unroll
    for (int k = 0; k < 4; ++k) hi[k] = f2bf(v[k]);
    *(u16x4*)(wo_bf + o) = hi;
  }
}

// ---------------- K1: in_proj split-bf16 MFMA GEMM ----------------
__global__ __launch_bounds__(256) void k_inproj(
    const uint16_t* __restrict__ a_hi, const uint16_t* __restrict__ a_lo,
    const uint16_t* __restrict__ w_hi, const uint16_t* __restrict__ w_lo,
    const float* __restrict__ bias, float* __restrict__ q_s,
    uint16_t* __restrict__ q_bf, uint16_t* __restrict__ k_bf,
    uint16_t* __restrict__ v_bf) {
  const int wave = threadIdx.x >> 6, lane = threadIdx.x & 63;
  const int wr = wave >> 1, wc = wave & 1;
  const int rif = lane & 15, kg = lane >> 4;
  const int rbase = blockIdx.x * 64 + wr * 32;
  const int cbase = blockIdx.y * 64 + wc * 32;
  f32x4 acc[2][2] = {};
  for (int ks = 0; ks < 512; ks += 32) {
    int kofs = ks + kg * 8;
    short8 aH[2], aL[2], bH[2], bL[2];
#pragma unroll
    for (int m = 0; m < 2; ++m) {
      size_t idx = (size_t)(rbase + m * 16 + rif) * 512 + kofs;
      aH[m] = ld8(a_hi + idx);
      aL[m] = ld8(a_lo + idx);
    }
#pragma unroll
    for (int n = 0; n < 2; ++n) {
      size_t idx = (size_t)(cbase + n * 16 + rif) * 512 + kofs;
      bH[n] = ld8(w_hi + idx);
      bL[n] = ld8(w_lo + idx);
    }
#pragma unroll
    for (int m = 0; m < 2; ++m)
#pragma unroll
      for (int n = 0; n < 2; ++n) {
        acc[m][n] = MFMA(aH[m], bH[n], acc[m][n]);
        acc[m][n] = MFMA(aH[m], bL[n], acc[m][n]);
        acc[m][n] = MFMA(aL[m], bH[n], acc[m][n]);
      }
  }
#pragma unroll
  for (int m = 0; m < 2; ++m)
#pragma unroll
    for (int n = 0; n < 2; ++n)
#pragma unroll
      for (int r = 0; r < 4; ++r) {
        int row = rbase + m * 16 + kg * 4 + r;
        int col = cbase + n * 16 + rif;
        float val = acc[m][n][r] + bias[col];
        int l = row >> 2, b = row & 3;
        int sel = col >> 9, h = (col >> 6) & 7, d = col & 63;
        size_t oidx = ((size_t)(b * 8 + h) * 512 + l) * 64 + d;
        if (sel == 0) {
          val *= 0.125f;  // 1/sqrt(64)
          q_s[oidx] = val;
          q_bf[oidx] = f2bf(val);
        } else if (sel == 1) {
          k_bf[oidx] = f2bf(val);
        } else {
          v_bf[oidx] = f2bf(val);
        }
      }
}

// ---------------- K2: content scores per (b,h), fp16 output ----------------
__global__ __launch_bounds__(256) void k_scores(const uint16_t* __restrict__ q_bf,
                                                const uint16_t* __restrict__ k_bf,
                                                __half* __restrict__ scores) {
  const int bh = blockIdx.x;
  const uint16_t* qb = q_bf + (size_t)bh * 512 * 64;
  const uint16_t* kb = k_bf + (size_t)bh * 512 * 64;
  const int wave = threadIdx.x >> 6, lane = threadIdx.x & 63;
  const int wr = wave >> 1, wc = wave & 1;
  const int rif = lane & 15, kg = lane >> 4;
  const int ibase = blockIdx.y * 64 + wr * 32;
  const int jbase = blockIdx.z * 64 + wc * 32;
  f32x4 acc[2][2] = {};
#pragma unroll
  for (int ks = 0; ks < 64; ks += 32) {
    int kofs = ks + kg * 8;
    short8 A[2], Bb[2];
#pragma unroll
    for (int m = 0; m < 2; ++m) A[m] = ld8(qb + (size_t)(ibase + m * 16 + rif) * 64 + kofs);
#pragma unroll
    for (int n = 0; n < 2; ++n) Bb[n] = ld8(kb + (size_t)(jbase + n * 16 + rif) * 64 + kofs);
#pragma unroll
    for (int m = 0; m < 2; ++m)
#pragma unroll
      for (int n = 0; n < 2; ++n) acc[m][n] = MFMA(A[m], Bb[n], acc[m][n]);
  }
  __half* sc = scores + (size_t)bh * 512 * 512;
#pragma unroll
  for (int m = 0; m < 2; ++m)
#pragma unroll
    for (int n = 0; n < 2; ++n)
#pragma unroll
      for (int r = 0; r < 4; ++r)
        sc[(size_t)(ibase + m * 16 + kg * 4 + r) * 512 + (jbase + n * 16 + rif)] =
            __float2half(acc[m][n][r]);
}

// ---------------- K3: mega — rk einsum + softmax + rv MFMA per (b,i) ----------------
__global__ __launch_bounds__(256) void k_mega(
    const float* __restrict__ relation_k, const float* __restrict__ relation_v,
    const float* __restrict__ q_s, const __half* __restrict__ scores,
    uint16_t* __restrict__ wprob, uint16_t* __restrict__ rv_bf) {
  __shared__ float qv[64 * 8];        // [d][h] fp32 scaled q
  __shared__ float sx[8 * 512];       // [h][j] rk-score partials
  __shared__ uint16_t wlds[8 * 512];  // [h][j] bf16 probs, XOR-swizzled
  const int b = blockIdx.x >> 9, i = blockIdx.x & 511;
  const int t = threadIdx.x;
  const int wave = t >> 6, lane = t & 63;
  // phase 1: q into LDS
  for (int e = t; e < 512; e += 256) {
    int h = e >> 6, d = e & 63;
    qv[d * 8 + h] = q_s[(((size_t)b * 8 + h) * 512 + i) * 64 + d];
  }
  __syncthreads();
  // phase 2: rk einsum (fp32 VALU, coalesced f32x4 over j)
  const int quad = t & 127, rep = t >> 7;
  const int j0 = quad * 4;
  const float* rkb = relation_k + ((size_t)b * 512 + i) * 32768;  // flat (D,L) view
  {
    f32x4 acc[8] = {};
    for (int dd = 0; dd < 32; ++dd) {
      int d = rep * 32 + dd;
      f32x4 rk4 = *(const f32x4*)(rkb + (size_t)d * 512 + j0);
      f32x4 q0 = *(const f32x4*)&qv[d * 8];
      f32x4 q1 = *(const f32x4*)&qv[d * 8 + 4];
#pragma unroll
      for (int h = 0; h < 4; ++h)
#pragma unroll
        for (int c = 0; c < 4; ++c) acc[h][c] += q0[h] * rk4[c];
#pragma unroll
      for (int h = 0; h < 4; ++h)
#pragma unroll
        for (int c = 0; c < 4; ++c) acc[4 + h][c] += q1[h] * rk4[c];
    }
    if (rep == 1) {
#pragma unroll
      for (int h = 0; h < 8; ++h) *(f32x4*)&sx[h * 512 + j0] = acc[h];
    }
    __syncthreads();
    if (rep == 0) {
#pragma unroll
      for (int h = 0; h < 8; ++h) {
        f32x4 o = *(f32x4*)&sx[h * 512 + j0];
#pragma unroll
        for (int c = 0; c < 4; ++c) o[c] += acc[h][c];
        *(f32x4*)&sx[h * 512 + j0] = o;
      }
    }
  }
  __syncthreads();
  // phase 3: softmax per (wave -> 2 heads); write w to LDS (swizzled) + global
  for (int hh = 0; hh < 2; ++hh) {
    int h = wave * 2 + hh;
    const __half* srow = scores + (((size_t)b * 8 + h) * 512 + i) * 512;
    float s[8], m = -1e30f;
#pragma unroll
    for (int jj = 0; jj < 8; ++jj) {
      int j = jj * 64 + lane;
      s[jj] = __half2float(srow[j]) + sx[h * 512 + j];
      m = fmaxf(m, s[jj]);
    }
    for (int o = 32; o > 0; o >>= 1) m = fmaxf(m, __shfl_xor(m, o));
    float ex[8], sum = 0.f;
#pragma unroll
    for (int jj = 0; jj < 8; ++jj) {
      ex[jj] = __expf(s[jj] - m);
      sum += ex[jj];
    }
    for (int o = 32; o > 0; o >>= 1) sum += __shfl_xor(sum, o);
    float r = 1.f / sum;
    uint16_t* wrow = wprob + (((size_t)b * 8 + h) * 512 + i) * 512;
#pragma unroll
    for (int jj = 0; jj < 8; ++jj) {
      int j = jj * 64 + lane;
      uint16_t wv = f2bf(ex[jj] * r);
      wrow[j] = wv;
      int ba = (h * 1024 + j * 2) ^ ((h & 7) << 4);
      *(uint16_t*)((char*)wlds + ba) = wv;
    }
  }
  __syncthreads();
  // phase 4: rv einsum via MFMA; wave = 16-wide d-tile
  const int rif = lane & 15, kg = lane >> 4;
  const int dt = wave;
  const float* rvb = relation_v + ((size_t)b * 512 + i) * 32768;  // [j][d]
  f32x4 acc2 = {};
  for (int ks = 0; ks < 16; ++ks) {
    short8 A = {};
    if (rif < 8) {
      int ba = (rif * 1024 + (ks * 32 + kg * 8) * 2) ^ ((rif & 7) << 4);
      A = *(const short8*)((const char*)wlds + ba);
    }
    uint16_t tb[8];
#pragma unroll
    for (int e = 0; e < 8; ++e)
      tb[e] = f2bf(rvb[(size_t)(ks * 32 + kg * 8 + e) * 64 + dt * 16 + rif]);
    short8 Bb = *(const short8*)tb;
    acc2 = MFMA(A, Bb, acc2);
  }
  if (kg < 2) {
#pragma unroll
    for (int r = 0; r < 4; ++r) {
      int h = kg * 4 + r;
      int d = dt * 16 + rif;
      rv_bf[((size_t)i * 4 + b) * 512 + h * 64 + d] = f2bf(acc2[r]);
    }
  }
}

// ---------------- K4: PV MFMA per (b,h), strided v loads ----------------
__global__ __launch_bounds__(256) void k_pv(const uint16_t* __restrict__ w_bf,
                                            const uint16_t* __restrict__ v_bf,
                                            uint16_t* __restrict__ pv_bf) {
  const int bh = blockIdx.x;
  const int b = bh >> 3, h = bh & 7;
  const uint16_t* wb = w_bf + (size_t)bh * 512 * 512;
  const uint16_t* vb = v_bf + (size_t)bh * 512 * 64;  // [j][d]
  const int wave = threadIdx.x >> 6, lane = threadIdx.x & 63;
  const int wr = wave >> 1, wc = wave & 1;
  const int rif = lane & 15, kg = lane >> 4;
  const int ibase = blockIdx.y * 64 + wr * 32;
  const int dbase = wc * 32;
  f32x4 acc[2][2] = {};
  for (int ks = 0; ks < 512; ks += 32) {
    int kofs = ks + kg * 8;
    short8 A[2], Bb[2];
#pragma unroll
    for (int m = 0; m < 2; ++m) A[m] = ld8(wb + (size_t)(ibase + m * 16 + rif) * 512 + kofs);
#pragma unroll
    for (int n = 0; n < 2; ++n) {
      uint16_t tb[8];
#pragma unroll
      for (int e = 0; e < 8; ++e) tb[e] = vb[(size_t)(kofs + e) * 64 + dbase + n * 16 + rif];
      Bb[n] = *(const short8*)tb;
    }
#pragma unroll
    for (int m = 0; m < 2; ++m)
#pragma unroll
      for (int n = 0; n < 2; ++n) acc[m][n] = MFMA(A[m], Bb[n], acc[m][n]);
  }
#pragma unroll
  for (int m = 0; m < 2; ++m)
#pragma unroll
    for (int n = 0; n < 2; ++n)
#pragma unroll
      for (int r = 0; r < 4; ++r) {
        int i = ibase + m * 16 + kg * 4 + r;
        int d = dbase + n * 16 + rif;
        pv_bf[((size_t)i * 4 + b) * 512 + h * 64 + d] = f2bf(acc[m][n][r]);
      }
}

// ---------------- K5: out_proj bf16 MFMA, dual-A (pv+rv) ----------------
__global__ __launch_bounds__(256) void k_outproj(const uint16_t* __restrict__ rv_a,
                                                 const uint16_t* __restrict__ pv_a,
                                                 const uint16_t* __restrict__ wo_bf,
                                                 const float* __restrict__ bias,
                                                 float* __restrict__ out) {
  const int wave = threadIdx.x >> 6, lane = threadIdx.x & 63;
  const int wr = wave >> 1, wc = wave & 1;
  const int rif = lane & 15, kg = lane >> 4;
  const int rbase = blockIdx.x * 64 + wr * 32;
  const int cbase = blockIdx.y * 64 + wc * 32;
  f32x4 acc[2][2] = {};
  for (int ks = 0; ks < 512; ks += 32) {
    int kofs = ks + kg * 8;
    short8 A[2], Bb[2];
#pragma unroll
    for (int m = 0; m < 2; ++m) {
      size_t idx = (size_t)(rbase + m * 16 + rif) * 512 + kofs;
      short8 p = ld8(pv_a + idx);
      short8 rr = ld8(rv_a + idx);
      uint16_t tb[8];
#pragma unroll
      for (int e = 0; e < 8; ++e)
        tb[e] = f2bf(bf2f((uint16_t)p[e]) + bf2f((uint16_t)rr[e]));
      A[m] = *(const short8*)tb;
    }
#pragma unroll
    for (int n = 0; n < 2; ++n) Bb[n] = ld8(wo_bf + (size_t)(cbase + n * 16 + rif) * 512 + kofs);
#pragma unroll
    for (int m = 0; m < 2; ++m)
#pragma unroll
      for (int n = 0; n < 2; ++n) acc[m][n] = MFMA(A[m], Bb[n], acc[m][n]);
  }
#pragma unroll
  for (int m = 0; m < 2; ++m)
#pragma unroll
    for (int n = 0; n < 2; ++n)
#pragma unroll
      for (int r = 0; r < 4; ++r) {
        int row = rbase + m * 16 + kg * 4 + r;
        int col = cbase + n * 16 + rif;
        out[(size_t)row * 512 + col] = acc[m][n][r] + bias[col];
      }
}

extern "C" void kernel_launch(void* const* d_in, const int* in_sizes, int n_in,
                              void* d_out, int out_size, void* d_ws, size_t ws_size,
                              hipStream_t stream) {
  const float* query = (const float*)d_in[0];
  const float* relation_k = (const float*)d_in[1];
  const float* relation_v = (const float*)d_in[2];
  const float* in_w = (const float*)d_in[3];
  const float* in_b = (const float*)d_in[4];
  const float* out_w = (const float*)d_in[5];
  const float* out_b = (const float*)d_in[6];
  float* out = (float*)d_out;
  char* ws = (char*)d_ws;

  uint16_t* a_hi  = (uint16_t*)(ws + 0);          // 2 MB
  uint16_t* a_lo  = (uint16_t*)(ws + 2097152);    // 2 MB
  uint16_t* w_hi  = (uint16_t*)(ws + 4194304);    // 1.5 MB
  uint16_t* w_lo  = (uint16_t*)(ws + 5767168);    // 1.5 MB
  uint16_t* wo_bf = (uint16_t*)(ws + 7340032);    // 0.5 MB
  float*    q_s   = (float*)   (ws + 7864320);    // 4 MB  (B,H,L,D) fp32
  uint16_t* q_bf  = (uint16_t*)(ws + 12058624);   // 2 MB
  uint16_t* k_bf  = (uint16_t*)(ws + 14155776);   // 2 MB
  uint16_t* v_bf  = (uint16_t*)(ws + 16252928);   // 2 MB
  uint16_t* rv_bf = (uint16_t*)(ws + 18350080);   // 2 MB  (L,B,E)
  uint16_t* pv_bf = (uint16_t*)(ws + 20447232);   // 2 MB  (L,B,E)
  uint16_t* wprob = (uint16_t*)(ws + 22544384);   // 16 MB (B,H,L,L) bf16
  __half*   sc_h  = (__half*)  (ws + 39321600);   // 8 MB  (B,H,L,L) fp16
  // total 47,710,208 bytes (< R1's 77 MB layout which fit)

  k_conv_all<<<dim3(2048), 256, 0, stream>>>(in_w, query, out_w, w_hi, w_lo, a_hi, a_lo, wo_bf);
  k_inproj<<<dim3(32, 24), 256, 0, stream>>>(a_hi, a_lo, w_hi, w_lo, in_b, q_s, q_bf, k_bf, v_bf);
  k_scores<<<dim3(32, 8, 8), 256, 0, stream>>>(q_bf, k_bf, sc_h);
  k_mega<<<dim3(2048), 256, 0, stream>>>(relation_k, relation_v, q_s, sc_h, wprob, rv_bf);
  k_pv<<<dim3(32, 8), 256, 0, stream>>>(wprob, v_bf, pv_bf);
  k_outproj<<<dim3(32, 8), 256, 0, stream>>>(rv_bf, pv_bf, wo_bf, out_b, out);
}